// Round 4
// baseline (320.267 us; speedup 1.0000x reference)
//
#include <hip/hip_runtime.h>
#include <math.h>

// EngramGating: B=16, S=16384, H=4, D=K=32. ntok = B*S = 262144.
// R9: R8 failed correctness (absmax 1.27). Layout audit passed; prime suspect
// is the hand-rolled v_permlane32_swap_b32 asm (unverified HW semantics; a
// full-crossed-exchange interpretation degenerates xsum32 to 2*x[l^32]).
// R9 replaces it with the harness-proven __shfl_xor(x,32) (R6 precedent),
// gives the emb stage its own LDS region (no kk-tile aliasing), and adds
// sched_barrier(0) after each lgkmcnt fence (rule-18 hardening).
// Structure otherwise = R7/R8: Wk held in VGPRs (d-split across wave halves,
// 4ch x 16d = 64 regs/lane), Wv in 4KB LDS, 4 tokens/wave-iter, kk-tile LDS
// transpose for phase-2 in-lane reductions, pipelined emb prefetch.

#define GRID    2048
#define EPS32   3.814697265625e-06f   // 32 * FLT_EPSILON
#define SQRT32  5.656854249492380f
#define LOG2E   1.4426950408889634f

// sum over lane pairs (l, l^32) — known-good primitive (R6 passed with this)
__device__ __forceinline__ float xsum32(float x) {
    return x + __shfl_xor(x, 32);
}
// xor-16 add within each 32-lane group; ds_swizzle bit mode (xor=16, and=0x1F)
// encoding 0x401F is the documented wave-reduction ladder step.
__device__ __forceinline__ float xadd16(float x) {
    return x + __int_as_float(
        __builtin_amdgcn_ds_swizzle(__float_as_int(x), 0x401F));
}
#define FENCE() do { \
    __asm__ volatile("s_waitcnt lgkmcnt(0)" ::: "memory"); \
    __builtin_amdgcn_sched_barrier(0); \
} while (0)

__global__ __launch_bounds__(256) void engram_kernel(
    const float* __restrict__ emb,   // [ntok,32]
    const float* __restrict__ hid,   // [ntok,4,32]
    const float* __restrict__ Wv,    // [32,32]
    const float* __restrict__ bv,    // [32]
    const float* __restrict__ Wk,    // [4,32,32]
    const float* __restrict__ bk,    // [4,32]
    const float* __restrict__ g1,    // [4,32]
    const float* __restrict__ g2,    // [4,32]
    float* __restrict__ out,         // [ntok,4,32]
    int ntok)
{
    // kk tile: 16 rows (t*4+h) x 32 k, 16B-block XOR-swizzled per row.
    __shared__ __align__(16) float KL[4][16 * 32];     // 8 KB
    __shared__ __align__(16) float EST[4][128];        // emb stage, 2 KB
    __shared__ __align__(16) float WvL[16 * 32 * 2];   // float2 [dp][k], 4 KB
    __shared__ __align__(16) float GL[4][16];          // gates, 256 B
    __shared__ __align__(16) float g12L[4 * 36];       // g1*g2 padded, 576 B
    __shared__ float bkL[160];                         // bk[4][32] + bv[32]

    const int tid  = threadIdx.x;
    const int wave = tid >> 6;
    const int lane = tid & 63;
    const int k    = lane & 31;
    const int h2   = lane >> 5;        // d-half this lane owns in phase 1

    // ---- stage Wv transposed: WvL2[dp*32+kk] = (Wv[kk][2dp], Wv[kk][2dp+1])
    for (int i = tid; i < 512; i += 256) {
        const int dp = i >> 5, kk = i & 31;
        ((float2*)WvL)[i] = make_float2(Wv[kk * 32 + 2 * dp],
                                        Wv[kk * 32 + 2 * dp + 1]);
    }
    if (tid < 128) g12L[(tid >> 5) * 36 + (tid & 31)] = g1[tid] * g2[tid];
    if (tid < 160) bkL[tid] = (tid < 128) ? bk[tid] : bv[tid - 128];

    // ---- Wk weights in registers: Wr[ch][dp] = Wk[ch][k][h2*16+2dp .. +1]
    float2 Wr[4][8];
    #pragma unroll
    for (int ch = 0; ch < 4; ++ch)
        #pragma unroll
        for (int dp = 0; dp < 8; ++dp)
            Wr[ch][dp] = *(const float2*)(Wk + (ch * 32 + k) * 32
                                             + h2 * 16 + 2 * dp);
    __syncthreads();

    float* const KLw  = KL[wave];
    float* const ESTw = EST[wave];
    const float2* const WvL2 = (const float2*)WvL;

    // phase-2 roles: lane = (row = t2*4+hh, kq = k-quarter)
    const int row = lane & 15;
    const int kq  = lane >> 4;
    const int t2  = row >> 2;
    const int hh  = row & 3;
    const int sw  = row & 7;

    const int tpb   = ntok / GRID;        // 128
    const int iters = tpb >> 4;           // 8 (16 tokens/block-iter)
    const int blk   = blockIdx.x * tpb;

    // pipeline: emb row for iter 0
    float2 ereg = *(const float2*)(emb + (blk + wave * 4) * 32 + lane * 2);

    for (int it = 0; it < iters; ++it) {
        const int tb = blk + it * 16 + wave * 4;     // this wave's 4 tokens

        // stage current emb (from pipelined regs), then prefetch next
        *(float2*)&ESTw[lane * 2] = ereg;
        {
            const int ntb = (it + 1 < iters) ? tb + 16 : tb;
            ereg = *(const float2*)(emb + ntb * 32 + lane * 2);
        }
        FENCE();

        float2 ka[4][4] = {};
        float  va[4]    = {0.f, 0.f, 0.f, 0.f};

        #pragma unroll
        for (int dp = 0; dp < 8; ++dp) {
            const float2 wv = WvL2[(h2 * 8 + dp) * 32 + k];
            #pragma unroll
            for (int t = 0; t < 4; ++t) {
                const float2 e2 = *(const float2*)&ESTw[t * 32 + h2 * 16 + 2 * dp];
                #pragma unroll
                for (int ch = 0; ch < 4; ++ch) {
                    ka[t][ch].x = fmaf(e2.x, Wr[ch][dp].x, ka[t][ch].x);
                    ka[t][ch].y = fmaf(e2.y, Wr[ch][dp].y, ka[t][ch].y);
                }
                va[t] = fmaf(e2.x, wv.x, fmaf(e2.y, wv.y, va[t]));
            }
        }

        // q loads for phase 2 (issued here; latency hides under combine+write)
        const float* qp = hid + (tb + t2) * 128 + hh * 32 + kq * 8;
        const float4 qa = *(const float4*)qp;
        const float4 qb = *(const float4*)(qp + 4);

        // combine halves + biases
        float ks[4][4], vs[4];
        #pragma unroll
        for (int t = 0; t < 4; ++t) {
            #pragma unroll
            for (int ch = 0; ch < 4; ++ch)
                ks[t][ch] = xsum32(ka[t][ch].x + ka[t][ch].y) + bkL[ch * 32 + k];
            vs[t] = xsum32(va[t]) + bkL[128 + k];
        }

        // write kk tile swizzled: half h2 writes rows for tokens h2*2+j
        {
            const int cblk = k >> 2, ksub = k & 3;
            #pragma unroll
            for (int j = 0; j < 2; ++j) {
                #pragma unroll
                for (int h = 0; h < 4; ++h) {
                    const int r = (h2 * 2 + j) * 4 + h;
                    const float val = h2 ? ks[2 + j][h] : ks[j][h];
                    KLw[r * 32 + (((cblk ^ (r & 7)) << 2) | ksub)] = val;
                }
            }
        }
        FENCE();

        // ---- phase 2: per-lane partial sums over 8 k, combine over 4 kq ----
        float A = 0.f, Bq = 0.f, C = 0.f;
        #pragma unroll
        for (int c = 0; c < 2; ++c) {
            const int cb = kq * 2 + c;
            const float4 kk4 = *(const float4*)&KLw[row * 32 + ((cb ^ sw) << 2)];
            const float4 g4  = *(const float4*)&g12L[hh * 36 + cb * 4];
            const float4 q   = c ? qb : qa;
            A  = fmaf(kk4.w, kk4.w, fmaf(kk4.z, kk4.z,
                 fmaf(kk4.y, kk4.y, fmaf(kk4.x, kk4.x, A))));
            Bq = fmaf(q.w, q.w, fmaf(q.z, q.z,
                 fmaf(q.y, q.y, fmaf(q.x, q.x, Bq))));
            C  = fmaf(kk4.w, q.w * g4.w, fmaf(kk4.z, q.z * g4.z,
                 fmaf(kk4.y, q.y * g4.y, fmaf(kk4.x, q.x * g4.x, C))));
        }
        A  = xsum32(xadd16(A));
        Bq = xsum32(xadd16(Bq));
        C  = xsum32(xadd16(C));

        // gate math (redundant across the 4 kq copies; written by kq==0)
        const float g  = C * SQRT32 * __builtin_amdgcn_rsqf(A + EPS32)
                                    * __builtin_amdgcn_rsqf(Bq + EPS32);
        const float rr = copysignf(sqrtf(fmaxf(fabsf(g), 1e-6f)), g);
        const float gl = 1.0f / (1.0f + __builtin_amdgcn_exp2f(-rr * LOG2E));
        if (lane < 16) GL[wave][row] = gl;
        FENCE();

        // ---- output: half h2 writes tokens h2*2+j, coalesced dwords ----
        #pragma unroll
        for (int j = 0; j < 2; ++j) {
            const float  vv = h2 ? vs[2 + j] : vs[j];
            const float4 gt = *(const float4*)&GL[wave][(h2 * 2 + j) * 4];
            const int    ob = (tb + h2 * 2 + j) * 128 + k;
            out[ob]      = gt.x * vv;
            out[ob + 32] = gt.y * vv;
            out[ob + 64] = gt.z * vv;
            out[ob + 96] = gt.w * vv;
        }
    }
}

extern "C" void kernel_launch(void* const* d_in, const int* in_sizes, int n_in,
                              void* d_out, int out_size, void* d_ws, size_t ws_size,
                              hipStream_t stream) {
    const float* emb = (const float*)d_in[0];
    const float* hid = (const float*)d_in[1];
    const float* Wv  = (const float*)d_in[2];
    const float* bv  = (const float*)d_in[3];
    const float* Wk  = (const float*)d_in[4];
    const float* bk  = (const float*)d_in[5];
    const float* g1  = (const float*)d_in[6];
    const float* g2  = (const float*)d_in[7];
    float* out = (float*)d_out;
    const int ntok = in_sizes[0] / 32;   // 262144
    engram_kernel<<<GRID, 256, 0, stream>>>(emb, hid, Wv, bv, Wk, bk, g1, g2,
                                            out, ntok);
}